// Round 1
// 1636.467 us; speedup vs baseline: 1.1175x; 1.1175x over previous
//
#include <hip/hip_runtime.h>

// WindowAttention (Swin): x[4096,49,512] -> qkv GEMM -> per-window-head attention
// (rel-pos bias + shift mask + softmax) -> proj GEMM.
// This round: both GEMMs moved from 128^2 single-buffered 2-barrier structure to the
// 256^2 / BK=64 8-phase pipelined schedule (T1 XCD swizzle + T2 LDS XOR swizzle +
// T3/T4 counted vmcnt + T5 setprio). Attention kernel unchanged.
//
// ws layout (bytes):
//   [0)                qkv bf16      [200704][1536]   616,562,688
//   [616562688)        x_bf bf16     [200704][512]    205,520,896  (reused as attn_out)
//   [822083584)        WqkvT bf16    [1536][512]        1,572,864
//   [823656448)        WprojT bf16   [512][512]           524,288
//   [824180736)        biasmask f32  [64][16][49][49]   9,834,496
//   total 834,015,232

typedef short  v8s __attribute__((ext_vector_type(8)));
typedef float  v4f __attribute__((ext_vector_type(4)));

#define B_WIN 4096
#define S_TOK 49
#define DIM   512
#define NH    16
#define HD    32
#define NW    64
#define M_TOT (B_WIN * S_TOK)   // 200704

__device__ __forceinline__ unsigned short f2bfu(float f) {
    unsigned u = __builtin_bit_cast(unsigned, f);
    u += 0x7fffu + ((u >> 16) & 1u);   // RNE (inputs finite)
    return (unsigned short)(u >> 16);
}

// ---------------- prep kernels ----------------

__global__ void cvt_x_kernel(const float4* __restrict__ x, ushort4* __restrict__ xb, int n4) {
    int i = blockIdx.x * 256 + threadIdx.x;
    if (i < n4) {
        float4 v = x[i];
        ushort4 o;
        o.x = f2bfu(v.x); o.y = f2bfu(v.y); o.z = f2bfu(v.z); o.w = f2bfu(v.w);
        xb[i] = o;
    }
}

// W [K][N] (f32, row-major) -> Wt [N][K] (bf16)
__global__ void cvt_wt_kernel(const float* __restrict__ W, unsigned short* __restrict__ Wt,
                              int K, int N) {
    int idx = blockIdx.x * 256 + threadIdx.x;
    if (idx >= N * K) return;
    int n = idx / K, k = idx - n * K;
    Wt[idx] = f2bfu(W[(size_t)k * N + n]);
}

// bm[(g*16+h)*2401 + i*49 + j] = bias_table[rel[i*49+j]*16 + h] + mask[g*2401 + i*49 + j]
__global__ void build_bm_kernel(const float* __restrict__ bias_table,
                                const int* __restrict__ rel_index,
                                const float* __restrict__ mask,
                                float* __restrict__ bm) {
    int idx = blockIdx.x * 256 + threadIdx.x;  // 64*16*2401 = 2,458,624 exact
    int ij = idx % 2401;
    int gh = idx / 2401;
    int h = gh & 15, g = gh >> 4;
    bm[idx] = bias_table[rel_index[ij] * NH + h] + mask[g * 2401 + ij];
}

// ---------------- GEMM: C[M][N] = A[M][K] @ Bt[N][K]^T + bias ----------------
// 256x256 tile, BK=64, 512 threads (8 waves as 2 wave-rows x 4 wave-cols; each wave
// owns a 128x64 output sub-tile = acc[8][4] 16x16 fragments).
//
// LDS (128 KiB): As[2],Bs[2] each [256 rows][64 k] bf16 (32 KiB), double-buffered over
// K-tiles (tile 2i -> buf0, 2i+1 -> buf1). Row = 128 B; 16B "slots" s=0..7 within a row
// are stored XOR-swizzled: LDS slot sigma holds global slot sigma^(row&7). Staging keeps
// the global_load_lds DEST linear and pre-swizzles the SOURCE address (both-sides
// involution); ds_read applies the same XOR -> conflict-free b128 reads.
//
// 8 phases per iteration (2 K-tiles). Per phase: ds_read one quadrant's fragments,
// issue one half-tile (128 rows) prefetch via 2x global_load_lds(16B), s_barrier,
// setprio(1) 16 MFMA setprio(0), s_barrier. Counted s_waitcnt vmcnt(4) ONLY at the
// end of phases 4 and 8 (4 newest loads = the 2 half-tiles staged this half-iter may
// stay in flight). Schedule safety: a half-tile region is re-staged only >=1 barrier
// after the last phase that ds_reads it; a tile's data is vmcnt-vouched by every wave
// before the barrier preceding its first ds_read.
template <int OUT_BF16>
__global__ __launch_bounds__(512, 2) void gemm256(
    const unsigned short* __restrict__ A,   // [M][K] bf16
    const unsigned short* __restrict__ Bt,  // [N][K] bf16
    const float* __restrict__ bias,         // [N]
    void* __restrict__ Cout,                // [M][N] bf16 or f32
    int M, int N, int K) {
    __shared__ alignas(16) char lds[131072];
    char* const As0 = lds;
    char* const As1 = lds + 32768;
    char* const Bs0 = lds + 65536;
    char* const Bs1 = lds + 98304;

    const int tid  = threadIdx.x;
    const int lane = tid & 63;
    const int wave = tid >> 6;
    const int r    = lane & 15;
    const int q    = lane >> 4;
    const int wr   = wave >> 2;   // 0..1 wave-row
    const int wc   = wave & 3;    // 0..3 wave-col

    // T1: XCD-aware bijective block swizzle (gridDim.x divisible by 8 for our shapes).
    // XCD x processes a contiguous chunk of logical tile ids -> A-stripe L2 reuse.
    const int nTx     = N >> 8;
    const int chunk   = gridDim.x >> 3;
    const int logical = (blockIdx.x & 7) * chunk + (blockIdx.x >> 3);
    const int bx = logical % nTx;
    const int by = logical / nTx;
    const int m0 = by << 8;
    const int n0 = bx << 8;

    const int K2 = K << 1;  // row stride, bytes

    // Staging source (pre-swizzled): LDS byte f = hf*16384 + l*8192 + tid*16 holds
    // global (row = hf*128 + l*64 + tid/8, slot = (tid&7) ^ (row&7)).  row&7 == rs&7.
    const int rs  = tid >> 3;
    const int skS = ((tid & 7) ^ (rs & 7)) << 4;
    const char* gAx = (const char*)(A  + (size_t)m0 * K) + (size_t)rs * K2 + skS;
    const char* gBx = (const char*)(Bt + (size_t)n0 * K) + (size_t)rs * K2 + skS;

#define STAGE(gsrc, ltile, hf, kt)                                               \
    {                                                                            \
        _Pragma("unroll")                                                        \
        for (int l_ = 0; l_ < 2; ++l_) {                                         \
            __builtin_amdgcn_global_load_lds(                                    \
                (const __attribute__((address_space(1))) unsigned int*)(         \
                    (gsrc) + (size_t)((hf) * 128 + l_ * 64) * K2 + (kt) * 128),  \
                (__attribute__((address_space(3))) unsigned int*)(               \
                    (ltile) + (hf) * 16384 + l_ * 8192 + tid * 16),              \
                16, 0, 0);                                                       \
        }                                                                        \
    }

    // Fragment reads. row&7 == r&7 (wave/frag offsets are multiples of 8 rows),
    // so the swizzled slot is lane-constant per ks: skb0/skb1.
    const int skb0 = ((q)     ^ (r & 7)) << 4;   // ks=0 slot byte
    const int skb1 = ((q + 4) ^ (r & 7)) << 4;   // ks=1 slot byte
    const int rowA = (wr * 128 + r) << 7;        // lane's A row byte offset in tile
    const int rowB = (wc * 64  + r) << 7;        // lane's B row byte offset in tile

#define RDA(tile, mi, ks) (*(const v8s*)((tile) + rowA + (mi) * 2048 + ((ks) ? skb1 : skb0)))
#define RDB(tile, ni, ks) (*(const v8s*)((tile) + rowB + (ni) * 2048 + ((ks) ? skb1 : skb0)))

    v4f acc[8][4] = {};
    v8s fa[4][2];   // current A-half fragments (mi x ks)
    v8s fb[4][2];   // all B fragments (ni x ks)

#define MM(ah, bh)                                                                   \
    {                                                                                \
        __builtin_amdgcn_s_setprio(1);                                               \
        _Pragma("unroll")                                                            \
        for (int i_ = 0; i_ < 4; ++i_)                                               \
            _Pragma("unroll")                                                        \
            for (int j_ = 0; j_ < 2; ++j_)                                           \
                _Pragma("unroll")                                                    \
                for (int k_ = 0; k_ < 2; ++k_)                                       \
                    acc[(ah) + i_][(bh) + j_] = __builtin_amdgcn_mfma_f32_16x16x32_bf16( \
                        fa[i_][k_], fb[(bh) + j_][k_], acc[(ah) + i_][(bh) + j_], 0, 0, 0); \
        __builtin_amdgcn_s_setprio(0);                                               \
    }

    const int NT     = K >> 6;   // K-tiles (even; 8 for K=512)
    const int niters = NT >> 1;

    // prologue: T0 fully + T1.B halves (T1.A staged at ph1/ph2 of iter 0)
    STAGE(gBx, Bs0, 0, 0); STAGE(gBx, Bs0, 1, 0);
    STAGE(gAx, As0, 0, 0); STAGE(gAx, As0, 1, 0);
    STAGE(gBx, Bs1, 0, 1); STAGE(gBx, Bs1, 1, 1);
    asm volatile("s_waitcnt vmcnt(4)" ::: "memory");   // T0's 8 loads landed
    __builtin_amdgcn_s_barrier();

    for (int i = 0; i < niters; ++i) {
        const int t1 = 2 * i + 1;
        const int t2 = 2 * i + 2;
        const int t3 = 2 * i + 3;
        const bool more = (i + 1) < niters;

        // ---- ph1: tile 2i, quad (A0,B0); stage T1.A0 -> As1.hf0
#pragma unroll
        for (int mi = 0; mi < 4; ++mi) { fa[mi][0] = RDA(As0, mi, 0); fa[mi][1] = RDA(As0, mi, 1); }
#pragma unroll
        for (int ni = 0; ni < 2; ++ni) { fb[ni][0] = RDB(Bs0, ni, 0); fb[ni][1] = RDB(Bs0, ni, 1); }
        STAGE(gAx, As1, 0, t1);
        __builtin_amdgcn_s_barrier();
        MM(0, 0);
        __builtin_amdgcn_s_barrier();

        // ---- ph2: quad (A0,B1); stage T1.A1 -> As1.hf1
#pragma unroll
        for (int ni = 2; ni < 4; ++ni) { fb[ni][0] = RDB(Bs0, ni, 0); fb[ni][1] = RDB(Bs0, ni, 1); }
        STAGE(gAx, As1, 1, t1);
        __builtin_amdgcn_s_barrier();
        MM(0, 2);
        __builtin_amdgcn_s_barrier();

        // ---- ph3: quad (A1,B1); stage T2.B0 -> Bs0.hf0 (Bs0 reads done by end ph2)
#pragma unroll
        for (int mi = 0; mi < 4; ++mi) { fa[mi][0] = RDA(As0, mi + 4, 0); fa[mi][1] = RDA(As0, mi + 4, 1); }
        if (more) STAGE(gBx, Bs0, 0, t2);
        __builtin_amdgcn_s_barrier();
        MM(4, 2);
        __builtin_amdgcn_s_barrier();

        // ---- ph4: quad (A1,B0); stage T2.B1; counted vmcnt -> tile t1 landed
        if (more) STAGE(gBx, Bs0, 1, t2);
        __builtin_amdgcn_s_barrier();
        MM(4, 0);
        if (more) { asm volatile("s_waitcnt vmcnt(4)" ::: "memory"); }  // leave T2.B0/B1 in flight
        else      { asm volatile("s_waitcnt vmcnt(0)" ::: "memory"); }  // final iter: drain
        __builtin_amdgcn_s_barrier();

        // ---- ph5: tile 2i+1, quad (A0,B0); stage T2.A0 -> As0.hf0 (As0 reads done by end ph3)
#pragma unroll
        for (int mi = 0; mi < 4; ++mi) { fa[mi][0] = RDA(As1, mi, 0); fa[mi][1] = RDA(As1, mi, 1); }
#pragma unroll
        for (int ni = 0; ni < 2; ++ni) { fb[ni][0] = RDB(Bs1, ni, 0); fb[ni][1] = RDB(Bs1, ni, 1); }
        if (more) STAGE(gAx, As0, 0, t2);
        __builtin_amdgcn_s_barrier();
        MM(0, 0);
        __builtin_amdgcn_s_barrier();

        // ---- ph6: quad (A0,B1); stage T2.A1 -> As0.hf1
#pragma unroll
        for (int ni = 2; ni < 4; ++ni) { fb[ni][0] = RDB(Bs1, ni, 0); fb[ni][1] = RDB(Bs1, ni, 1); }
        if (more) STAGE(gAx, As0, 1, t2);
        __builtin_amdgcn_s_barrier();
        MM(0, 2);
        __builtin_amdgcn_s_barrier();

        // ---- ph7: quad (A1,B1); stage T3.B0 -> Bs1.hf0 (Bs1 reads done by end ph6)
#pragma unroll
        for (int mi = 0; mi < 4; ++mi) { fa[mi][0] = RDA(As1, mi + 4, 0); fa[mi][1] = RDA(As1, mi + 4, 1); }
        if (more) STAGE(gBx, Bs1, 0, t3);
        __builtin_amdgcn_s_barrier();
        MM(4, 2);
        __builtin_amdgcn_s_barrier();

        // ---- ph8: quad (A1,B0); stage T3.B1; counted vmcnt -> tile t2 landed
        if (more) STAGE(gBx, Bs1, 1, t3);
        __builtin_amdgcn_s_barrier();
        MM(4, 0);
        if (more) { asm volatile("s_waitcnt vmcnt(4)" ::: "memory"); }  // leave T3.B0/B1 in flight
        __builtin_amdgcn_s_barrier();
    }

    // ---- epilogue: C write (+bias), bf16 or f32
    const int nb = n0 + wc * 64 + r;
    const int mb = m0 + wr * 128 + q * 4;
#pragma unroll
    for (int ni = 0; ni < 4; ++ni) {
        const int n = nb + ni * 16;
        const float bv = bias[n];
#pragma unroll
        for (int mi = 0; mi < 8; ++mi) {
#pragma unroll
            for (int rg = 0; rg < 4; ++rg) {
                const int m = mb + mi * 16 + rg;
                float val = acc[mi][ni][rg] + bv;
                if (OUT_BF16)
                    ((unsigned short*)Cout)[(size_t)m * N + n] = f2bfu(val);
                else
                    ((float*)Cout)[(size_t)m * N + n] = val;
            }
        }
    }
#undef STAGE
#undef RDA
#undef RDB
#undef MM
}

// ---------------- attention: one wave per (window, head) ----------------
// scores = (q@k^T)*scale + bm  (64x64 padded; 16 MFMAs), in-register softmax,
// P -> LDS (A-layout), V -> LDS transposed, out = P@V (16 MFMAs).
__global__ __launch_bounds__(256) void attn_kernel(
    const unsigned short* __restrict__ qkv,  // [200704][1536] bf16
    const float* __restrict__ bm,            // [64][16][49][49]
    unsigned short* __restrict__ out) {      // [200704][512] bf16
    const int w    = blockIdx.x;
    const int wave = threadIdx.x >> 6;
    const int h    = blockIdx.y * 4 + wave;
    const int lane = threadIdx.x & 63;
    const int r    = lane & 15;
    const int quad = lane >> 4;
    const int g    = w & (NW - 1);
    const size_t base = (size_t)w * S_TOK;

    __shared__ unsigned short pbuf[4][64 * 72];  // 36,864 B (stride 72: 144B rows, 16B-aligned)
    __shared__ unsigned short vbuf[4][32 * 72];  // 18,432 B
    unsigned short* p_lds = pbuf[wave];
    unsigned short* vt    = vbuf[wave];

    // ---- stage V transposed: vt[d][j] = v[j][d], zero-pad j in [49,64) ----
    {
        int j = lane;
        union { uint4 q[4]; unsigned short s[32]; } vv;
        if (j < S_TOK) {
            const uint4* vrow = (const uint4*)(qkv + (base + j) * 1536 + 1024 + (size_t)h * HD);
#pragma unroll
            for (int c = 0; c < 4; ++c) vv.q[c] = vrow[c];
        } else {
#pragma unroll
            for (int c = 0; c < 4; ++c) vv.q[c] = make_uint4(0, 0, 0, 0);
        }
#pragma unroll
        for (int d = 0; d < HD; ++d) vt[d * 72 + j] = vv.s[d];
    }

    // ---- load Q/K fragments (A-layout: row=lane&15, k=quad*8..+7), zero-pad ----
    v8s zf = {0, 0, 0, 0, 0, 0, 0, 0};
    v8s aq[4], bk[4];
#pragma unroll
    for (int t = 0; t < 4; ++t) {
        int row = 16 * t + r;
        if (row < S_TOK) {
            const unsigned short* qp = qkv + (base + row) * 1536 + (size_t)h * HD + quad * 8;
            aq[t] = *(const v8s*)qp;
            bk[t] = *(const v8s*)(qp + 512);
        } else {
            aq[t] = zf;
            bk[t] = zf;
        }
    }

    // ---- scores ----
    v4f sc[4][4] = {};
#pragma unroll
    for (int i = 0; i < 4; ++i)
#pragma unroll
        for (int j = 0; j < 4; ++j)
            sc[i][j] = __builtin_amdgcn_mfma_f32_16x16x32_bf16(aq[i], bk[j], sc[i][j], 0, 0, 0);

    // ---- scale + bias/mask + row softmax (rows live in 16-lane quads) ----
    const float scale = 0.17677669529663687f;  // 32^-0.5
    const float* bmh = bm + (size_t)(g * NH + h) * 2401;
#pragma unroll
    for (int it = 0; it < 4; ++it) {
#pragma unroll
        for (int rg = 0; rg < 4; ++rg) {
            int i = 16 * it + quad * 4 + rg;
            float s[4];
#pragma unroll
            for (int jt = 0; jt < 4; ++jt) {
                int j = 16 * jt + r;
                float v = sc[it][jt][rg] * scale;
                if (i < S_TOK && j < S_TOK) v += bmh[i * 49 + j];
                if (j >= S_TOK) v = -1e30f;
                s[jt] = v;
            }
            float mx = fmaxf(fmaxf(s[0], s[1]), fmaxf(s[2], s[3]));
#pragma unroll
            for (int d = 1; d < 16; d <<= 1) mx = fmaxf(mx, __shfl_xor(mx, d));
            float sum = 0.f;
#pragma unroll
            for (int jt = 0; jt < 4; ++jt) { s[jt] = __expf(s[jt] - mx); sum += s[jt]; }
#pragma unroll
            for (int d = 1; d < 16; d <<= 1) sum += __shfl_xor(sum, d);
            float inv = 1.0f / sum;
#pragma unroll
            for (int jt = 0; jt < 4; ++jt) sc[it][jt][rg] = s[jt] * inv;
        }
    }

    // ---- P (C-layout) -> LDS row-major [i][j] for A-layout reads ----
#pragma unroll
    for (int it = 0; it < 4; ++it)
#pragma unroll
        for (int jt = 0; jt < 4; ++jt)
#pragma unroll
            for (int rg = 0; rg < 4; ++rg) {
                int i = 16 * it + quad * 4 + rg;
                int j = 16 * jt + r;
                p_lds[i * 72 + j] = f2bfu(sc[it][jt][rg]);
            }

    __syncthreads();  // lgkm drain: p_lds/vt writes visible to own ds_reads

    // ---- out = P @ V : M=64(i), K=64(j), N=32(d) ----
    v4f oacc[4][2] = {};
#pragma unroll
    for (int kt = 0; kt < 2; ++kt) {
        v8s bv[2];
#pragma unroll
        for (int nt = 0; nt < 2; ++nt)
            bv[nt] = *(const v8s*)(vt + (16 * nt + r) * 72 + 32 * kt + quad * 8);
#pragma unroll
        for (int it = 0; it < 4; ++it) {
            v8s ap = *(const v8s*)(p_lds + (16 * it + r) * 72 + 32 * kt + quad * 8);
#pragma unroll
            for (int nt = 0; nt < 2; ++nt)
                oacc[it][nt] = __builtin_amdgcn_mfma_f32_16x16x32_bf16(ap, bv[nt], oacc[it][nt], 0, 0, 0);
        }
    }

    // ---- store attn_out bf16 [m][512] at col h*32 ----
#pragma unroll
    for (int it = 0; it < 4; ++it)
#pragma unroll
        for (int nt = 0; nt < 2; ++nt)
#pragma unroll
            for (int rg = 0; rg < 4; ++rg) {
                int i = 16 * it + quad * 4 + rg;
                if (i < S_TOK)
                    out[(base + i) * DIM + h * HD + 16 * nt + r] = f2bfu(oacc[it][nt][rg]);
            }
}

// ---------------- launch ----------------

extern "C" void kernel_launch(void* const* d_in, const int* in_sizes, int n_in,
                              void* d_out, int out_size, void* d_ws, size_t ws_size,
                              hipStream_t stream) {
    const float* x          = (const float*)d_in[0];
    const float* mask       = (const float*)d_in[1];
    const float* Wqkv       = (const float*)d_in[2];
    const float* bqkv       = (const float*)d_in[3];
    const float* Wproj      = (const float*)d_in[4];
    const float* bproj      = (const float*)d_in[5];
    const float* bias_table = (const float*)d_in[6];
    const int*   rel_index  = (const int*)d_in[7];
    float* out = (float*)d_out;

    char* ws = (char*)d_ws;
    unsigned short* qkv    = (unsigned short*)(ws);                  // 616,562,688
    unsigned short* xbf    = (unsigned short*)(ws + 616562688);      // 205,520,896 (→ attn_out)
    unsigned short* wqkvt  = (unsigned short*)(ws + 822083584);      // 1,572,864
    unsigned short* wprojt = (unsigned short*)(ws + 823656448);      // 524,288
    float*          bm     = (float*)(ws + 824180736);               // 9,834,496

    // prep
    cvt_x_kernel<<<100352, 256, 0, stream>>>((const float4*)x, (ushort4*)xbf, 25690112);
    cvt_wt_kernel<<<(1536 * 512) / 256, 256, 0, stream>>>(Wqkv, wqkvt, 512, 1536);
    cvt_wt_kernel<<<(512 * 512) / 256, 256, 0, stream>>>(Wproj, wprojt, 512, 512);
    build_bm_kernel<<<(NW * NH * 2401) / 256, 256, 0, stream>>>(bias_table, rel_index, mask, bm);

    // qkv = x @ Wqkv + bqkv   (M=200704, N=1536, K=512) -> bf16
    // grid 784*6 = 4704 blocks (divisible by 8 for the XCD swizzle)
    gemm256<1><<<dim3(4704), 512, 0, stream>>>(xbf, wqkvt, bqkv, qkv, M_TOT, 1536, 512);

    // attention -> attn_out (aliases xbf; x_bf is dead after the qkv GEMM)
    attn_kernel<<<dim3(B_WIN, 4), 256, 0, stream>>>(qkv, bm, xbf);

    // out = attn_out @ Wproj + bproj  (M=200704, N=512, K=512) -> f32
    // grid 784*2 = 1568 blocks
    gemm256<0><<<dim3(1568), 512, 0, stream>>>(xbf, wprojt, bproj, out, M_TOT, 512, 512);
}